// Round 9
// baseline (578.959 us; speedup 1.0000x reference)
//
#include <hip/hip_runtime.h>

// Problem geometry (fixed by setup_inputs)
constexpr int N_ = 8, C_ = 8, H_ = 1024, W_ = 1024;

constexpr int TW = 256;
constexpr int THREADS = 256;

// k2 tiling: 256x16, sobel halo 1 -> 18 staged rows
constexpr int T2H = 16, R2_ = 18;

// Gaussian kernel: cv2.getGaussianKernel(5, 2), normalized
constexpr float G0_ = 0.15246914f;
constexpr float G1_ = 0.22184130f;
constexpr float G2_ = 0.25137912f;

__device__ __forceinline__ float block_reduce(float v, float* red4) {
    #pragma unroll
    for (int off = 32; off > 0; off >>= 1) v += __shfl_down(v, off);
    const int lane = threadIdx.x & 63, wid = threadIdx.x >> 6;
    if (lane == 0) red4[wid] = v;
    __syncthreads();
    float s = 0.f;
    if (threadIdx.x == 0) s = red4[0] + red4[1] + red4[2] + red4[3];
    __syncthreads();
    return s;
}

// branchless reflect-101 for H=W=1024, arg range [-2, 1057]
__device__ __forceinline__ int refl(int y) {
    int a = (y < 0) ? -y : y;
    int b = 2046 - a;
    return (a < b) ? a : b;
}

// k1: barrier-free rolling-window streaming.
// Block = 4 waves x 8-row strips = 32 rows x 256 cols. Grid (4,32,8) = 1024 = 4 blocks/CU.
// No shuffles, no staging LDS; x-neighbors via unaligned float4 loads (L1 absorbs overlap).
__global__ __launch_bounds__(THREADS, 4)
void k1_blur_sums(const float* __restrict__ outp,
                  const float* __restrict__ refp,
                  const float* __restrict__ msp,
                  float* __restrict__ o2p,
                  double* __restrict__ part_ms,
                  double* __restrict__ part_ref)
{
    __shared__ float o2p_lds[32 * 256];   // exclusive per-thread slots, no sync needed
    __shared__ float red4[4];

    const int t = threadIdx.x, lane = t & 63, wv = t >> 6;
    const int tx = blockIdx.x, ty = blockIdx.y, n = blockIdx.z;
    const int x0 = tx << 8;
    const int y0w = (ty << 5) + (wv << 3);     // wave's 8-row strip
    const int cg = x0 + (lane << 2);           // thread's absolute cols cg..cg+3
    const bool le = (cg == 0);                 // left image edge (tx=0, lane=0)
    const bool re = (cg == 1020);              // right image edge (tx=3, lane=63)

    // one row: 2 unaligned float4 loads -> h-blurred float4 + raw centers
    auto hrow = [&](const float* plane, int gy, float4& hout, float4& rawout) {
        const float* rowg = plane + ((size_t)gy << 10);
        float4 A, B;   // A = cols cg-2..cg+1, B = cols cg+2..cg+5
        if (le) { float4 v = *(const float4*)rowg;            // r0..r3
                  A.x = v.z; A.y = v.y; A.z = v.x; A.w = v.y; }      // refl: r2,r1,r0,r1
        else    { A = *(const float4*)(rowg + cg - 2); }
        if (re) { float4 v = *(const float4*)(rowg + 1020);   // r1020..r1023
                  B.x = v.z; B.y = v.w; B.z = v.z; B.w = v.y; }      // r1022,r1023,refl->1022,1021
        else    { B = *(const float4*)(rowg + cg + 2); }
        hout.x = G0_*(A.x+B.x) + G1_*(A.y+A.w) + G2_*A.z;
        hout.y = G0_*(A.y+B.y) + G1_*(A.z+B.x) + G2_*A.w;
        hout.z = G0_*(A.z+B.z) + G1_*(A.w+B.y) + G2_*B.x;
        hout.w = G0_*(A.w+B.w) + G1_*(B.x+B.z) + G2_*B.y;
        rawout.x = A.z; rawout.y = A.w; rawout.z = B.x; rawout.w = B.y;
    };

    float accMs = 0.f, accRef = 0.f;

    for (int c = 0; c < C_; ++c) {
        const float* plane = outp + ((size_t)(n * C_ + c) << 20);

        // warmup: fill 4-row h-blur window + raw-center ring
        float4 h0, h1, h2, h3, h4, ctr0, ctr1, mtmp;
        hrow(plane, refl(y0w - 2), h0, mtmp);
        hrow(plane, refl(y0w - 1), h1, mtmp);
        hrow(plane, y0w,           h2, ctr0);
        hrow(plane, y0w + 1,       h3, ctr1);

        #pragma unroll
        for (int j = 0; j < 8; ++j) {
            float4 mnew;
            hrow(plane, refl(y0w + j + 2), h4, mnew);

            float4 b;
            b.x = G0_*(h0.x+h4.x) + G1_*(h1.x+h3.x) + G2_*h2.x;
            b.y = G0_*(h0.y+h4.y) + G1_*(h1.y+h3.y) + G2_*h2.y;
            b.z = G0_*(h0.z+h4.z) + G1_*(h1.z+h3.z) + G2_*h2.z;
            b.w = G0_*(h0.w+h4.w) + G1_*(h1.w+h3.w) + G2_*h2.w;

            const size_t gidx = ((size_t)(n * C_ + c) * H_ + (y0w + j)) * W_ + cg;
            float4 m  = *(const float4*)(msp + gidx);
            float4 rr = *(const float4*)(refp + gidx);

            accMs  += fabsf(b.x - m.x) + fabsf(b.y - m.y) + fabsf(b.z - m.z) + fabsf(b.w - m.w);
            accRef += fabsf(ctr0.x - rr.x) + fabsf(ctr0.y - rr.y)
                    + fabsf(ctr0.z - rr.z) + fabsf(ctr0.w - rr.w);

            float4* slot = (float4*)&o2p_lds[((wv << 3) + j) * 256 + (lane << 2)];
            if (c == 0) {
                *slot = ctr0;
            } else {
                float4 s = *slot;
                s.x += ctr0.x; s.y += ctr0.y; s.z += ctr0.z; s.w += ctr0.w;
                *slot = s;
            }

            h0 = h1; h1 = h2; h2 = h3; h3 = h4;
            ctr0 = ctr1; ctr1 = mnew;
        }
    }

    // write out2pan (channel mean), coalesced 1KB per wave per row
    #pragma unroll
    for (int j = 0; j < 8; ++j) {
        float4 s = *(float4*)&o2p_lds[((wv << 3) + j) * 256 + (lane << 2)];
        s.x *= 0.125f; s.y *= 0.125f; s.z *= 0.125f; s.w *= 0.125f;
        *(float4*)&o2p[((size_t)n * H_ + (y0w + j)) * W_ + cg] = s;
    }

    float sMs  = block_reduce(accMs, red4);
    float sRef = block_reduce(accRef, red4);
    if (t == 0) {
        const int bid = (n * gridDim.y + ty) * gridDim.x + tx;
        part_ms[bid]  = (double)sMs;
        part_ref[bid] = (double)sRef;
    }
}

__global__ __launch_bounds__(THREADS)
void k2_sobel(const float* __restrict__ pan,
              const float* __restrict__ o2p,
              double* __restrict__ part_pan)
{
    __shared__ float d[R2_ * 256];   // staged rows = image rows y0-1 .. y0+16
    __shared__ float sd[R2_ * 2];    // side cols: [r][0]=x0-1, [r][1]=x0+256
    __shared__ float red4[4];

    const int t = threadIdx.x;
    const int tx = blockIdx.x, ty = blockIdx.y, n = blockIdx.z;
    const int x0 = tx * TW, y0 = ty * T2H;
    const size_t base = (size_t)n * (H_ * W_);

    for (int i = t; i < R2_ * 64; i += THREADS) {
        const int r = i >> 6, cf = (i & 63) << 2;
        const int gy = y0 + r - 1;
        float4 v = {0,0,0,0};
        if (gy >= 0 && gy < H_) {
            const size_t gi = base + ((size_t)gy << 10) + x0 + cf;
            float4 p4 = *(const float4*)(pan + gi);
            float4 q4 = *(const float4*)(o2p + gi);
            v.x = p4.x - q4.x; v.y = p4.y - q4.y; v.z = p4.z - q4.z; v.w = p4.w - q4.w;
        }
        *(float4*)&d[(r << 8) + cf] = v;
    }
    if (t < R2_ * 2) {
        const int r = t >> 1, s = t & 1;
        const int gy = y0 + r - 1;
        const int gx = s ? (x0 + 256) : (x0 - 1);
        float v = 0.f;
        if (gy >= 0 && gy < H_ && gx >= 0 && gx < W_) {
            const size_t gi = base + ((size_t)gy << 10) + gx;
            v = pan[gi] - o2p[gi];
        }
        sd[(r << 1) + s] = v;
    }
    __syncthreads();

    const int c0  = (t & 63) << 2;
    const int sr0 = (t >> 6) << 2;   // staged rows sr0..sr0+5; outputs sr0+1..sr0+4

    float4 hx[6], hs[6];
    #pragma unroll
    for (int k = 0; k < 6; ++k) {
        const int r = sr0 + k;                         // <= 17
        const float* rowp = d + (r << 8);
        float lft = (c0 == 0)   ? sd[r << 1]       : rowp[c0 - 1];
        float4 m4 = *(const float4*)(rowp + c0);
        float rgt = (c0 == 252) ? sd[(r << 1) + 1] : rowp[c0 + 4];
        hx[k].x = m4.y - lft;  hx[k].y = m4.z - m4.x;
        hx[k].z = m4.w - m4.y; hx[k].w = rgt - m4.z;
        hs[k].x = lft + 2.f*m4.x + m4.y;  hs[k].y = m4.x + 2.f*m4.y + m4.z;
        hs[k].z = m4.y + 2.f*m4.z + m4.w; hs[k].w = m4.z + 2.f*m4.w + rgt;
    }

    float acc = 0.f;
    #pragma unroll
    for (int j = 0; j < 4; ++j) {   // output centered at staged row sr0+j+1
        float4 gx4, gy4;
        gx4.x = hx[j].x + 2.f*hx[j+1].x + hx[j+2].x;
        gx4.y = hx[j].y + 2.f*hx[j+1].y + hx[j+2].y;
        gx4.z = hx[j].z + 2.f*hx[j+1].z + hx[j+2].z;
        gx4.w = hx[j].w + 2.f*hx[j+1].w + hx[j+2].w;
        gy4.x = hs[j+2].x - hs[j].x;  gy4.y = hs[j+2].y - hs[j].y;
        gy4.z = hs[j+2].z - hs[j].z;  gy4.w = hs[j+2].w - hs[j].w;
        acc += fabsf(gx4.x) + fabsf(gx4.y) + fabsf(gx4.z) + fabsf(gx4.w)
             + fabsf(gy4.x) + fabsf(gy4.y) + fabsf(gy4.z) + fabsf(gy4.w);
    }

    float s = block_reduce(acc, red4);
    if (t == 0) {
        const int bid = (n * gridDim.y + ty) * gridDim.x + tx;
        part_pan[bid] = (double)s;
    }
}

__global__ __launch_bounds__(256)
void k3_final(const double* __restrict__ part_ms,
              const double* __restrict__ part_ref,
              const double* __restrict__ part_pan,
              int nb1, int nb2, float* __restrict__ outv)
{
    __shared__ double sMs[256], sRef[256], sPan[256];
    const int t = threadIdx.x;
    double a = 0.0, b = 0.0, c = 0.0;
    for (int i = t; i < nb1; i += 256) {
        a += part_ms[i];
        b += part_ref[i];
    }
    for (int i = t; i < nb2; i += 256) {
        c += part_pan[i];
    }
    sMs[t] = a; sRef[t] = b; sPan[t] = c;
    __syncthreads();
    for (int s = 128; s > 0; s >>= 1) {
        if (t < s) { sMs[t] += sMs[t + s]; sRef[t] += sRef[t + s]; sPan[t] += sPan[t + s]; }
        __syncthreads();
    }
    if (t == 0) {
        const double inv_big = 1.0 / (double)(N_ * C_ * H_ * W_);
        const double inv_pan = 1.0 / (double)(N_ * 1 * H_ * W_);
        double total = sMs[0] * inv_big + sRef[0] * inv_big + sPan[0] * inv_pan;
        outv[0] = (float)total;
    }
}

extern "C" void kernel_launch(void* const* d_in, const int* in_sizes, int n_in,
                              void* d_out, int out_size, void* d_ws, size_t ws_size,
                              hipStream_t stream) {
    const float* refp = (const float*)d_in[0];
    const float* pan  = (const float*)d_in[1];
    const float* msp  = (const float*)d_in[2];
    const float* outp = (const float*)d_in[3];

    const int NB1 = 4 * 32 * 8;                   // k1 grid: (4, 32, 8) = 1024
    const int NB2 = (W_ / TW) * (H_ / T2H) * N_;  // k2 grid: (4, 64, 8) = 2048

    char* ws = (char*)d_ws;
    float* o2p = (float*)ws;
    size_t o2p_bytes = (size_t)N_ * H_ * W_ * sizeof(float);
    double* part_ms  = (double*)(ws + o2p_bytes);
    double* part_ref = part_ms + NB1;
    double* part_pan = part_ref + NB1;

    dim3 grid1(4, 32, 8);
    k1_blur_sums<<<grid1, THREADS, 0, stream>>>(outp, refp, msp, o2p, part_ms, part_ref);
    dim3 grid2(W_ / TW, H_ / T2H, N_);
    k2_sobel<<<grid2, THREADS, 0, stream>>>(pan, o2p, part_pan);
    k3_final<<<1, 256, 0, stream>>>(part_ms, part_ref, part_pan, NB1, NB2, (float*)d_out);
}

// Round 10
// 164.977 us; speedup vs baseline: 3.5093x; 3.5093x over previous
//
#include <hip/hip_runtime.h>

// Problem geometry (fixed by setup_inputs)
constexpr int N_ = 8, C_ = 8, H_ = 1024, W_ = 1024;
constexpr int THREADS = 256;

// Fused kernel: block = 256x32 output strip; staged rows 36 (blur halo 2)
// Gaussian kernel: cv2.getGaussianKernel(5, 2), normalized
constexpr float G0_ = 0.15246914f;
constexpr float G1_ = 0.22184130f;
constexpr float G2_ = 0.25137912f;

#define GLOAD_LDS16(gp, lp) __builtin_amdgcn_global_load_lds( \
    (const __attribute__((address_space(1))) void*)(gp),      \
    (__attribute__((address_space(3))) void*)(lp), 16, 0, 0)
#define GLOAD_LDS4(gp, lp) __builtin_amdgcn_global_load_lds(  \
    (const __attribute__((address_space(1))) void*)(gp),      \
    (__attribute__((address_space(3))) void*)(lp), 4, 0, 0)

__device__ __forceinline__ float block_reduce(float v, float* red4) {
    #pragma unroll
    for (int off = 32; off > 0; off >>= 1) v += __shfl_down(v, off);
    const int lane = threadIdx.x & 63, wid = threadIdx.x >> 6;
    if (lane == 0) red4[wid] = v;
    __syncthreads();
    float s = 0.f;
    if (threadIdx.x == 0) s = red4[0] + red4[1] + red4[2] + red4[3];
    __syncthreads();
    return s;
}

// branchless reflect-101 for H=W=1024, arg range [-2, 1057]
__device__ __forceinline__ int refl(int y) {
    int a = (y < 0) ? -y : y;
    int b = 2046 - a;
    return (a < b) ? a : b;
}

__global__ __launch_bounds__(THREADS)
void k1_fused(const float* __restrict__ outp,
              const float* __restrict__ refp,
              const float* __restrict__ msp,
              const float* __restrict__ panp,
              double* __restrict__ part_ms,
              double* __restrict__ part_ref,
              double* __restrict__ part_pan)
{
    __shared__ float til[36 * 256];     // staged out rows y0-2..y0+33; later reused as d-tile
    __shared__ float hal[36 * 4];       // x-halo cols {x0-2, x0-1, x0+256, x0+257} per staged row
    __shared__ float o2p_int[32 * 256]; // channel sums, rows y0..y0+31 (exclusive slots)
    __shared__ float o2p_top[256];      // channel sums, row y0-1  (staged row 1)
    __shared__ float o2p_bot[256];      // channel sums, row y0+32 (staged row 34)
    __shared__ float o2pL[34], o2pR[34];// channel sums, cols x0-1 / x0+256, rows y0-1..y0+32
    __shared__ float dL[34], dR[34];    // d side cols for sobel
    __shared__ float red4[4];

    const int t = threadIdx.x, lane = t & 63, wv = t >> 6;

    // chunked XCD swizzle: each XCD owns one n-plane (1024 blocks, 8 XCDs, 128 each)
    const int flat = blockIdx.x + (blockIdx.y << 2) + (blockIdx.z << 7);
    const int nf = ((flat & 7) << 7) + (flat >> 3);
    const int tx = nf & 3, ty = (nf >> 2) & 31, n = nf >> 7;

    const int x0 = tx << 8, y0 = ty << 5;
    const int y0w = y0 + (wv << 3);     // wave's 8 output rows
    const int c0 = lane << 2;           // thread's local cols c0..c0+3
    const int s0 = wv << 3;             // thread's first staged-window row

    // ---- stage channel c: 9 full-row 1KB wave-loads + 144 halo scalars
    auto stage = [&](int c) {
        const float* plane = outp + ((size_t)(n * C_ + c) << 20);
        #pragma unroll
        for (int k = 0; k < 9; ++k) {
            const int r = wv + (k << 2);               // rows wv, wv+4, ..., wv+32
            const int gy = refl(y0 + r - 2);
            GLOAD_LDS16(plane + ((size_t)gy << 10) + x0 + (lane << 2), &til[r << 8]);
        }
        int slot = -1, base = 0;
        if (wv == 0)                    { slot = lane;       base = 0;   }
        else if (wv == 1)               { slot = 64 + lane;  base = 64;  }
        else if (wv == 2 && lane < 16)  { slot = 128 + lane; base = 128; }
        if (slot >= 0) {
            const int r = slot >> 2, cdx = slot & 3;
            const int gy = refl(y0 + r - 2);
            const int gx = refl(x0 + ((cdx < 2) ? cdx - 2 : cdx + 254));
            GLOAD_LDS4(plane + ((size_t)gy << 10) + gx, &hal[base]);
        }
    };

    // h-blur one staged row s for this thread's cols; also return raw centers
    auto hrowL = [&](int s, float4& hout, float4& raw) {
        const float* rowp = &til[s << 8];
        float2 l2 = (c0 == 0)   ? *(const float2*)&hal[(s << 2)]
                                : *(const float2*)(rowp + c0 - 2);
        float4 m4 = *(const float4*)(rowp + c0);
        float2 r2 = (c0 == 252) ? *(const float2*)&hal[(s << 2) + 2]
                                : *(const float2*)(rowp + c0 + 4);
        hout.x = G0_ * (l2.x + m4.z) + G1_ * (l2.y + m4.y) + G2_ * m4.x;
        hout.y = G0_ * (l2.y + m4.w) + G1_ * (m4.x + m4.z) + G2_ * m4.y;
        hout.z = G0_ * (m4.x + r2.x) + G1_ * (m4.y + m4.w) + G2_ * m4.z;
        hout.w = G0_ * (m4.y + r2.y) + G1_ * (m4.z + r2.x) + G2_ * m4.w;
        raw = m4;
    };

    float accMs = 0.f, accRef = 0.f;

    for (int c = 0; c < C_; ++c) {
        stage(c);
        __syncthreads();   // drains gload_lds; til/hal ready for all waves

        float4 h0, h1, h2, h3, h4, ctr0, ctr1, mtmp;
        hrowL(s0 + 0, h0, mtmp);
        hrowL(s0 + 1, h1, mtmp);
        hrowL(s0 + 2, h2, ctr0);
        hrowL(s0 + 3, h3, ctr1);

        #pragma unroll
        for (int j = 0; j < 8; ++j) {
            float4 mnew;
            hrowL(s0 + j + 4, h4, mnew);

            float4 b;
            b.x = G0_*(h0.x+h4.x) + G1_*(h1.x+h3.x) + G2_*h2.x;
            b.y = G0_*(h0.y+h4.y) + G1_*(h1.y+h3.y) + G2_*h2.y;
            b.z = G0_*(h0.z+h4.z) + G1_*(h1.z+h3.z) + G2_*h2.z;
            b.w = G0_*(h0.w+h4.w) + G1_*(h1.w+h3.w) + G2_*h2.w;

            const size_t gidx = ((size_t)(n * C_ + c) * H_ + (y0w + j)) * W_ + x0 + c0;
            float4 m  = *(const float4*)(msp + gidx);
            float4 rr = *(const float4*)(refp + gidx);

            accMs  += fabsf(b.x - m.x) + fabsf(b.y - m.y) + fabsf(b.z - m.z) + fabsf(b.w - m.w);
            accRef += fabsf(ctr0.x - rr.x) + fabsf(ctr0.y - rr.y)
                    + fabsf(ctr0.z - rr.z) + fabsf(ctr0.w - rr.w);

            // o2p channel-sum: exclusive slot, no sync needed
            float4* slot = (float4*)&o2p_int[(((wv << 3) + j) << 8) + c0];
            if (c == 0) {
                *slot = ctr0;
            } else {
                float4 s = *slot;
                s.x += ctr0.x; s.y += ctr0.y; s.z += ctr0.z; s.w += ctr0.w;
                *slot = s;
            }

            h0 = h1; h1 = h2; h2 = h3; h3 = h4;
            ctr0 = ctr1; ctr1 = mnew;
        }

        // o2p halo rows (staged rows 1 and 34) and side cols from hal
        if (t < 128) {
            const int which = t >> 6;                 // 0 -> top, 1 -> bottom
            const int f4c = (t & 63) << 2;
            const float* srcrow = &til[(which ? 34 : 1) << 8];
            float4 v = *(const float4*)(srcrow + f4c);
            float* dst = which ? &o2p_bot[f4c] : &o2p_top[f4c];
            if (c == 0) { dst[0] = v.x; dst[1] = v.y; dst[2] = v.z; dst[3] = v.w; }
            else        { dst[0] += v.x; dst[1] += v.y; dst[2] += v.z; dst[3] += v.w; }
        }
        if (t < 34) {
            float v = hal[((t + 1) << 2) + 1];                 // col x0-1, staged row t+1
            o2pL[t] = (c == 0) ? v : o2pL[t] + v;
        } else if (t >= 64 && t < 98) {
            float v = hal[((t - 63) << 2) + 2];                // col x0+256, staged row t-63
            o2pR[t - 64] = (c == 0) ? v : o2pR[t - 64] + v;
        }

        __syncthreads();   // til/hal reads done before next channel's staging
    }

    // ---- build d = pan - o2p/8 into til (rows 0..33 = image rows y0-1..y0+32), zero-padded
    const float* pan = panp + ((size_t)n << 20);
    for (int i = t; i < 34 * 64; i += THREADS) {
        const int rr = i >> 6, f4c = (i & 63) << 2;
        const int gy = y0 - 1 + rr;
        float4 dv = {0, 0, 0, 0};
        if (gy >= 0 && gy < H_) {
            float4 p4 = *(const float4*)(pan + ((size_t)gy << 10) + x0 + f4c);
            const float* osrc = (rr == 0) ? &o2p_top[f4c]
                              : (rr == 33) ? &o2p_bot[f4c]
                              : &o2p_int[((rr - 1) << 8) + f4c];
            dv.x = p4.x - 0.125f * osrc[0];
            dv.y = p4.y - 0.125f * osrc[1];
            dv.z = p4.z - 0.125f * osrc[2];
            dv.w = p4.w - 0.125f * osrc[3];
        }
        *(float4*)&til[(rr << 8) + f4c] = dv;
    }
    if (t < 34) {
        const int gy = y0 - 1 + t, gx = x0 - 1;
        dL[t] = (gy >= 0 && gy < H_ && gx >= 0)
              ? (pan[((size_t)gy << 10) + gx] - 0.125f * o2pL[t]) : 0.f;
    } else if (t >= 64 && t < 98) {
        const int i = t - 64, gy = y0 - 1 + i, gx = x0 + 256;
        dR[i] = (gy >= 0 && gy < H_ && gx < W_)
              ? (pan[((size_t)gy << 10) + gx] - 0.125f * o2pR[i]) : 0.f;
    }
    __syncthreads();

    // ---- sobel on d (zero-padded), rolling 3-row window; outputs = own 8 rows
    auto srow = [&](int r, float4& hx, float4& hs) {
        const float* rowp = &til[r << 8];
        float lft = (c0 == 0)   ? dL[r] : rowp[c0 - 1];
        float4 m4 = *(const float4*)(rowp + c0);
        float rgt = (c0 == 252) ? dR[r] : rowp[c0 + 4];
        hx.x = m4.y - lft;  hx.y = m4.z - m4.x;
        hx.z = m4.w - m4.y; hx.w = rgt - m4.z;
        hs.x = lft + 2.f*m4.x + m4.y;  hs.y = m4.x + 2.f*m4.y + m4.z;
        hs.z = m4.y + 2.f*m4.z + m4.w; hs.w = m4.z + 2.f*m4.w + rgt;
    };

    float accPan = 0.f;
    {
        float4 hx0, hx1, hx2, hs0, hs1, hs2;
        srow(s0 + 0, hx0, hs0);
        srow(s0 + 1, hx1, hs1);
        #pragma unroll
        for (int j = 0; j < 8; ++j) {
            srow(s0 + j + 2, hx2, hs2);
            float4 gx4, gy4;
            gx4.x = hx0.x + 2.f*hx1.x + hx2.x;
            gx4.y = hx0.y + 2.f*hx1.y + hx2.y;
            gx4.z = hx0.z + 2.f*hx1.z + hx2.z;
            gx4.w = hx0.w + 2.f*hx1.w + hx2.w;
            gy4.x = hs2.x - hs0.x;  gy4.y = hs2.y - hs0.y;
            gy4.z = hs2.z - hs0.z;  gy4.w = hs2.w - hs0.w;
            accPan += fabsf(gx4.x) + fabsf(gx4.y) + fabsf(gx4.z) + fabsf(gx4.w)
                    + fabsf(gy4.x) + fabsf(gy4.y) + fabsf(gy4.z) + fabsf(gy4.w);
            hx0 = hx1; hx1 = hx2; hs0 = hs1; hs1 = hs2;
        }
    }

    float sMs  = block_reduce(accMs, red4);
    float sRef = block_reduce(accRef, red4);
    float sPan = block_reduce(accPan, red4);
    if (t == 0) {
        part_ms[nf]  = (double)sMs;
        part_ref[nf] = (double)sRef;
        part_pan[nf] = (double)sPan;
    }
}

__global__ __launch_bounds__(256)
void k3_final(const double* __restrict__ part_ms,
              const double* __restrict__ part_ref,
              const double* __restrict__ part_pan,
              int nb, float* __restrict__ outv)
{
    __shared__ double sMs[256], sRef[256], sPan[256];
    const int t = threadIdx.x;
    double a = 0.0, b = 0.0, c = 0.0;
    for (int i = t; i < nb; i += 256) {
        a += part_ms[i];
        b += part_ref[i];
        c += part_pan[i];
    }
    sMs[t] = a; sRef[t] = b; sPan[t] = c;
    __syncthreads();
    for (int s = 128; s > 0; s >>= 1) {
        if (t < s) { sMs[t] += sMs[t + s]; sRef[t] += sRef[t + s]; sPan[t] += sPan[t + s]; }
        __syncthreads();
    }
    if (t == 0) {
        const double inv_big = 1.0 / (double)(N_ * C_ * H_ * W_);
        const double inv_pan = 1.0 / (double)(N_ * 1 * H_ * W_);
        double total = sMs[0] * inv_big + sRef[0] * inv_big + sPan[0] * inv_pan;
        outv[0] = (float)total;
    }
}

extern "C" void kernel_launch(void* const* d_in, const int* in_sizes, int n_in,
                              void* d_out, int out_size, void* d_ws, size_t ws_size,
                              hipStream_t stream) {
    const float* refp = (const float*)d_in[0];
    const float* pan  = (const float*)d_in[1];
    const float* msp  = (const float*)d_in[2];
    const float* outp = (const float*)d_in[3];

    const int NB = 4 * 32 * 8;   // 1024 blocks

    double* part_ms  = (double*)d_ws;
    double* part_ref = part_ms + NB;
    double* part_pan = part_ref + NB;

    dim3 grid(4, 32, 8);
    k1_fused<<<grid, THREADS, 0, stream>>>(outp, refp, msp, pan,
                                           part_ms, part_ref, part_pan);
    k3_final<<<1, 256, 0, stream>>>(part_ms, part_ref, part_pan, NB, (float*)d_out);
}

// Round 11
// 150.110 us; speedup vs baseline: 3.8569x; 1.0990x over previous
//
#include <hip/hip_runtime.h>

// Problem geometry (fixed by setup_inputs)
constexpr int N_ = 8, C_ = 8, H_ = 1024, W_ = 1024;
constexpr int THREADS = 256;

// Gaussian kernel: cv2.getGaussianKernel(5, 2), normalized
constexpr float G0_ = 0.15246914f;
constexpr float G1_ = 0.22184130f;
constexpr float G2_ = 0.25137912f;

#define GLOAD_LDS16(gp, lp) __builtin_amdgcn_global_load_lds( \
    (const __attribute__((address_space(1))) void*)(gp),      \
    (__attribute__((address_space(3))) void*)(lp), 16, 0, 0)
#define GLOAD_LDS4(gp, lp) __builtin_amdgcn_global_load_lds(  \
    (const __attribute__((address_space(1))) void*)(gp),      \
    (__attribute__((address_space(3))) void*)(lp), 4, 0, 0)

__device__ __forceinline__ float block_reduce(float v, float* red4) {
    #pragma unroll
    for (int off = 32; off > 0; off >>= 1) v += __shfl_down(v, off);
    const int lane = threadIdx.x & 63, wid = threadIdx.x >> 6;
    if (lane == 0) red4[wid] = v;
    __syncthreads();
    float s = 0.f;
    if (threadIdx.x == 0) s = red4[0] + red4[1] + red4[2] + red4[3];
    __syncthreads();
    return s;
}

// branchless reflect-101 for H=W=1024, arg range [-2, 1057]
__device__ __forceinline__ int refl(int y) {
    int a = (y < 0) ? -y : y;
    int b = 2046 - a;
    return (a < b) ? a : b;
}

__global__ __launch_bounds__(THREADS)
void k1_fused(const float* __restrict__ outp,
              const float* __restrict__ refp,
              const float* __restrict__ msp,
              const float* __restrict__ panp,
              double* __restrict__ part_ms,
              double* __restrict__ part_ref,
              double* __restrict__ part_pan)
{
    __shared__ float til[36 * 256];     // staged out rows y0-2..y0+33; later reused as d-tile
    __shared__ float hal[36 * 4];       // x-halo cols {x0-2, x0-1, x0+256, x0+257} per staged row
    __shared__ float o2p_top[256];      // channel sums, row y0-1  (staged row 1)
    __shared__ float o2p_bot[256];      // channel sums, row y0+32 (staged row 34)
    __shared__ float o2pL[34], o2pR[34];// channel sums, cols x0-1 / x0+256, rows y0-1..y0+32
    __shared__ float dL[34], dR[34];    // d side cols for sobel
    __shared__ float red4[4];

    const int t = threadIdx.x, lane = t & 63, wv = t >> 6;

    // chunked XCD swizzle: each XCD owns one n-plane (1024 blocks, 8 XCDs, 128 each)
    const int flat = blockIdx.x + (blockIdx.y << 2) + (blockIdx.z << 7);
    const int nf = ((flat & 7) << 7) + (flat >> 3);
    const int tx = nf & 3, ty = (nf >> 2) & 31, n = nf >> 7;

    const int x0 = tx << 8, y0 = ty << 5;
    const int y0w = y0 + (wv << 3);     // wave's 8 output rows
    const int c0 = lane << 2;           // thread's local cols c0..c0+3
    const int s0 = wv << 3;             // thread's first staged-window row

    // ---- stage channel c: 9 full-row 1KB wave-loads + 144 halo scalars
    auto stage = [&](int c) {
        const float* plane = outp + ((size_t)(n * C_ + c) << 20);
        #pragma unroll
        for (int k = 0; k < 9; ++k) {
            const int r = wv + (k << 2);               // rows wv, wv+4, ..., wv+32
            const int gy = refl(y0 + r - 2);
            GLOAD_LDS16(plane + ((size_t)gy << 10) + x0 + (lane << 2), &til[r << 8]);
        }
        int slot = -1, base = 0;
        if (wv == 0)                    { slot = lane;       base = 0;   }
        else if (wv == 1)               { slot = 64 + lane;  base = 64;  }
        else if (wv == 2 && lane < 16)  { slot = 128 + lane; base = 128; }
        if (slot >= 0) {
            const int r = slot >> 2, cdx = slot & 3;
            const int gy = refl(y0 + r - 2);
            const int gx = refl(x0 + ((cdx < 2) ? cdx - 2 : cdx + 254));
            GLOAD_LDS4(plane + ((size_t)gy << 10) + gx, &hal[base]);
        }
    };

    // h-blur one staged row s for this thread's cols; also return raw centers
    auto hrowL = [&](int s, float4& hout, float4& raw) {
        const float* rowp = &til[s << 8];
        float2 l2 = (c0 == 0)   ? *(const float2*)&hal[(s << 2)]
                                : *(const float2*)(rowp + c0 - 2);
        float4 m4 = *(const float4*)(rowp + c0);
        float2 r2 = (c0 == 252) ? *(const float2*)&hal[(s << 2) + 2]
                                : *(const float2*)(rowp + c0 + 4);
        hout.x = G0_ * (l2.x + m4.z) + G1_ * (l2.y + m4.y) + G2_ * m4.x;
        hout.y = G0_ * (l2.y + m4.w) + G1_ * (m4.x + m4.z) + G2_ * m4.y;
        hout.z = G0_ * (m4.x + r2.x) + G1_ * (m4.y + m4.w) + G2_ * m4.z;
        hout.w = G0_ * (m4.y + r2.y) + G1_ * (m4.z + r2.x) + G2_ * m4.w;
        raw = m4;
    };

    float accMs = 0.f, accRef = 0.f;
    float4 o2pacc[8];   // per-thread o2p channel sums (8 rows x 4 cols), registers only

    for (int c = 0; c < C_; ++c) {
        stage(c);
        __syncthreads();   // drains gload_lds; til/hal ready for all waves

        float4 h0, h1, h2, h3, h4, ctr0, ctr1, mtmp;
        hrowL(s0 + 0, h0, mtmp);
        hrowL(s0 + 1, h1, mtmp);
        hrowL(s0 + 2, h2, ctr0);
        hrowL(s0 + 3, h3, ctr1);

        #pragma unroll
        for (int j = 0; j < 8; ++j) {
            float4 mnew;
            hrowL(s0 + j + 4, h4, mnew);

            float4 b;
            b.x = G0_*(h0.x+h4.x) + G1_*(h1.x+h3.x) + G2_*h2.x;
            b.y = G0_*(h0.y+h4.y) + G1_*(h1.y+h3.y) + G2_*h2.y;
            b.z = G0_*(h0.z+h4.z) + G1_*(h1.z+h3.z) + G2_*h2.z;
            b.w = G0_*(h0.w+h4.w) + G1_*(h1.w+h3.w) + G2_*h2.w;

            const size_t gidx = ((size_t)(n * C_ + c) * H_ + (y0w + j)) * W_ + x0 + c0;
            float4 m  = *(const float4*)(msp + gidx);
            float4 rr = *(const float4*)(refp + gidx);

            accMs  += fabsf(b.x - m.x) + fabsf(b.y - m.y) + fabsf(b.z - m.z) + fabsf(b.w - m.w);
            accRef += fabsf(ctr0.x - rr.x) + fabsf(ctr0.y - rr.y)
                    + fabsf(ctr0.z - rr.z) + fabsf(ctr0.w - rr.w);

            // o2p channel-sum in registers (statically indexed after unroll)
            if (c == 0) {
                o2pacc[j] = ctr0;
            } else {
                o2pacc[j].x += ctr0.x; o2pacc[j].y += ctr0.y;
                o2pacc[j].z += ctr0.z; o2pacc[j].w += ctr0.w;
            }

            h0 = h1; h1 = h2; h2 = h3; h3 = h4;
            ctr0 = ctr1; ctr1 = mnew;
        }

        // o2p halo rows (staged rows 1 and 34) and side cols from hal
        if (t < 128) {
            const int which = t >> 6;                 // 0 -> top, 1 -> bottom
            const int f4c = (t & 63) << 2;
            const float* srcrow = &til[(which ? 34 : 1) << 8];
            float4 v = *(const float4*)(srcrow + f4c);
            float* dst = which ? &o2p_bot[f4c] : &o2p_top[f4c];
            if (c == 0) { dst[0] = v.x; dst[1] = v.y; dst[2] = v.z; dst[3] = v.w; }
            else        { dst[0] += v.x; dst[1] += v.y; dst[2] += v.z; dst[3] += v.w; }
        }
        if (t < 34) {
            float v = hal[((t + 1) << 2) + 1];                 // col x0-1, staged row t+1
            o2pL[t] = (c == 0) ? v : o2pL[t] + v;
        } else if (t >= 64 && t < 98) {
            float v = hal[((t - 63) << 2) + 2];                // col x0+256, staged row t-63
            o2pR[t - 64] = (c == 0) ? v : o2pR[t - 64] + v;
        }

        __syncthreads();   // til/hal reads done before next channel's staging
    }

    // ---- build d = pan - o2p/8 into til (rows 0..33 = image rows y0-1..y0+32), zero-padded
    const float* pan = panp + ((size_t)n << 20);

    // interior rows: each thread writes its own 8 rows (d row = strip row + 1)
    #pragma unroll
    for (int j = 0; j < 8; ++j) {
        const int gy = y0w + j;
        float4 p4 = *(const float4*)(pan + ((size_t)gy << 10) + x0 + c0);
        float4 dv;
        dv.x = p4.x - 0.125f * o2pacc[j].x;
        dv.y = p4.y - 0.125f * o2pacc[j].y;
        dv.z = p4.z - 0.125f * o2pacc[j].z;
        dv.w = p4.w - 0.125f * o2pacc[j].w;
        *(float4*)&til[(((wv << 3) + j + 1) << 8) + c0] = dv;
    }
    // halo rows 0 (y0-1) and 33 (y0+32)
    if (t < 128) {
        const int which = t >> 6;                     // 0 -> row 0, 1 -> row 33
        const int f4c = (t & 63) << 2;
        const int gy = which ? (y0 + 32) : (y0 - 1);
        float4 dv = {0, 0, 0, 0};
        if (gy >= 0 && gy < H_) {
            float4 p4 = *(const float4*)(pan + ((size_t)gy << 10) + x0 + f4c);
            const float* osrc = which ? &o2p_bot[f4c] : &o2p_top[f4c];
            dv.x = p4.x - 0.125f * osrc[0];
            dv.y = p4.y - 0.125f * osrc[1];
            dv.z = p4.z - 0.125f * osrc[2];
            dv.w = p4.w - 0.125f * osrc[3];
        }
        *(float4*)&til[((which ? 33 : 0) << 8) + f4c] = dv;
    }
    if (t < 34) {
        const int gy = y0 - 1 + t, gx = x0 - 1;
        dL[t] = (gy >= 0 && gy < H_ && gx >= 0)
              ? (pan[((size_t)gy << 10) + gx] - 0.125f * o2pL[t]) : 0.f;
    } else if (t >= 64 && t < 98) {
        const int i = t - 64, gy = y0 - 1 + i, gx = x0 + 256;
        dR[i] = (gy >= 0 && gy < H_ && gx < W_)
              ? (pan[((size_t)gy << 10) + gx] - 0.125f * o2pR[i]) : 0.f;
    }
    __syncthreads();

    // ---- sobel on d (zero-padded), rolling 3-row window; outputs = own 8 rows
    auto srow = [&](int r, float4& hx, float4& hs) {
        const float* rowp = &til[r << 8];
        float lft = (c0 == 0)   ? dL[r] : rowp[c0 - 1];
        float4 m4 = *(const float4*)(rowp + c0);
        float rgt = (c0 == 252) ? dR[r] : rowp[c0 + 4];
        hx.x = m4.y - lft;  hx.y = m4.z - m4.x;
        hx.z = m4.w - m4.y; hx.w = rgt - m4.z;
        hs.x = lft + 2.f*m4.x + m4.y;  hs.y = m4.x + 2.f*m4.y + m4.z;
        hs.z = m4.y + 2.f*m4.z + m4.w; hs.w = m4.z + 2.f*m4.w + rgt;
    };

    float accPan = 0.f;
    {
        float4 hx0, hx1, hx2, hs0, hs1, hs2;
        srow(s0 + 0, hx0, hs0);
        srow(s0 + 1, hx1, hs1);
        #pragma unroll
        for (int j = 0; j < 8; ++j) {
            srow(s0 + j + 2, hx2, hs2);
            float4 gx4, gy4;
            gx4.x = hx0.x + 2.f*hx1.x + hx2.x;
            gx4.y = hx0.y + 2.f*hx1.y + hx2.y;
            gx4.z = hx0.z + 2.f*hx1.z + hx2.z;
            gx4.w = hx0.w + 2.f*hx1.w + hx2.w;
            gy4.x = hs2.x - hs0.x;  gy4.y = hs2.y - hs0.y;
            gy4.z = hs2.z - hs0.z;  gy4.w = hs2.w - hs0.w;
            accPan += fabsf(gx4.x) + fabsf(gx4.y) + fabsf(gx4.z) + fabsf(gx4.w)
                    + fabsf(gy4.x) + fabsf(gy4.y) + fabsf(gy4.z) + fabsf(gy4.w);
            hx0 = hx1; hx1 = hx2; hs0 = hs1; hs1 = hs2;
        }
    }

    float sMs  = block_reduce(accMs, red4);
    float sRef = block_reduce(accRef, red4);
    float sPan = block_reduce(accPan, red4);
    if (t == 0) {
        part_ms[nf]  = (double)sMs;
        part_ref[nf] = (double)sRef;
        part_pan[nf] = (double)sPan;
    }
}

__global__ __launch_bounds__(256)
void k3_final(const double* __restrict__ part_ms,
              const double* __restrict__ part_ref,
              const double* __restrict__ part_pan,
              int nb, float* __restrict__ outv)
{
    __shared__ double sMs[256], sRef[256], sPan[256];
    const int t = threadIdx.x;
    double a = 0.0, b = 0.0, c = 0.0;
    for (int i = t; i < nb; i += 256) {
        a += part_ms[i];
        b += part_ref[i];
        c += part_pan[i];
    }
    sMs[t] = a; sRef[t] = b; sPan[t] = c;
    __syncthreads();
    for (int s = 128; s > 0; s >>= 1) {
        if (t < s) { sMs[t] += sMs[t + s]; sRef[t] += sRef[t + s]; sPan[t] += sPan[t + s]; }
        __syncthreads();
    }
    if (t == 0) {
        const double inv_big = 1.0 / (double)(N_ * C_ * H_ * W_);
        const double inv_pan = 1.0 / (double)(N_ * 1 * H_ * W_);
        double total = sMs[0] * inv_big + sRef[0] * inv_big + sPan[0] * inv_pan;
        outv[0] = (float)total;
    }
}

extern "C" void kernel_launch(void* const* d_in, const int* in_sizes, int n_in,
                              void* d_out, int out_size, void* d_ws, size_t ws_size,
                              hipStream_t stream) {
    const float* refp = (const float*)d_in[0];
    const float* pan  = (const float*)d_in[1];
    const float* msp  = (const float*)d_in[2];
    const float* outp = (const float*)d_in[3];

    const int NB = 4 * 32 * 8;   // 1024 blocks

    double* part_ms  = (double*)d_ws;
    double* part_ref = part_ms + NB;
    double* part_pan = part_ref + NB;

    dim3 grid(4, 32, 8);
    k1_fused<<<grid, THREADS, 0, stream>>>(outp, refp, msp, pan,
                                           part_ms, part_ref, part_pan);
    k3_final<<<1, 256, 0, stream>>>(part_ms, part_ref, part_pan, NB, (float*)d_out);
}